// Round 1
// baseline (106.344 us; speedup 1.0000x reference)
//
#include <hip/hip_runtime.h>

// KDPointToPointLoss: B=8, C=3, N=M=4096, fp32.
// loss[b] = (1/(3N)) * sum_n min_m ||src[b,:,n] - tgt[b,:,m]||^2
// (sum over c of diff^2 for the argmin target == the min squared distance,
//  so no index gather is needed.)

#define B_ 8
#define N_ 4096
#define M_ 4096
#define CH_STRIDE 4096        // stride between c-planes (floats)
#define BATCH_STRIDE 12288    // 3*4096 floats per batch

__global__ void zero_out_kernel(float* out) {
    int t = threadIdx.x;
    if (t < B_) out[t] = 0.0f;
}

// grid: 512 blocks (64 per batch), block: 256 threads.
// Each block: 64 source points x full M.
//   lane ls = tid & 63  -> local source point
//   wave  w = tid >> 6  -> M-chunk [w*1024, w*1024+1024)
// Target loads are wave-uniform (same address across all 64 lanes) ->
// single broadcast L1 transaction per load.
__global__ __launch_bounds__(256, 2)
void nn_loss_kernel(const float* __restrict__ src,
                    const float* __restrict__ tgt,
                    float* __restrict__ out) {
    const int tid   = threadIdx.x;
    const int blk   = blockIdx.x;
    const int b     = blk >> 6;                 // batch
    const int ls    = tid & 63;                 // local source
    const int chunk = tid >> 6;                 // m-chunk (== wave id)
    const int n     = ((blk & 63) << 6) + ls;   // source index in batch

    const float* sb = src + b * BATCH_STRIDE;
    const float sx = sb[n];
    const float sy = sb[n + CH_STRIDE];
    const float sz = sb[n + 2 * CH_STRIDE];

    const float* tb = tgt + b * BATCH_STRIDE;
    const int mBeg = chunk << 10;               // 1024 targets per wave
    const int mEnd = mBeg + 1024;

    float best0 = 3.4e38f, best1 = 3.4e38f;

    #pragma unroll 2
    for (int m = mBeg; m < mEnd; m += 4) {
        const float4 x4 = *(const float4*)(tb + m);
        const float4 y4 = *(const float4*)(tb + CH_STRIDE + m);
        const float4 z4 = *(const float4*)(tb + 2 * CH_STRIDE + m);

        float dx, dy, dz, d;
        dx = sx - x4.x; dy = sy - y4.x; dz = sz - z4.x;
        d = dx * dx + dy * dy + dz * dz;
        best0 = fminf(best0, d);

        dx = sx - x4.y; dy = sy - y4.y; dz = sz - z4.y;
        d = dx * dx + dy * dy + dz * dz;
        best1 = fminf(best1, d);

        dx = sx - x4.z; dy = sy - y4.z; dz = sz - z4.z;
        d = dx * dx + dy * dy + dz * dz;
        best0 = fminf(best0, d);

        dx = sx - x4.w; dy = sy - y4.w; dz = sz - z4.w;
        d = dx * dx + dy * dy + dz * dz;
        best1 = fminf(best1, d);
    }

    float best = fminf(best0, best1);

    // Reduce min across the 4 chunks for each of the 64 sources.
    __shared__ float red[256];
    red[(chunk << 6) + ls] = best;
    __syncthreads();

    if (tid < 64) {
        float m0 = fminf(red[tid], red[tid + 64]);
        float m1 = fminf(red[tid + 128], red[tid + 192]);
        float mn = fminf(m0, m1);   // min squared distance for source `tid`

        // Wave-64 sum across the 64 sources of this block.
        #pragma unroll
        for (int off = 32; off > 0; off >>= 1)
            mn += __shfl_down(mn, off, 64);

        if (tid == 0)
            atomicAdd(out + b, mn * (1.0f / (3.0f * (float)N_)));
    }
}

extern "C" void kernel_launch(void* const* d_in, const int* in_sizes, int n_in,
                              void* d_out, int out_size, void* d_ws, size_t ws_size,
                              hipStream_t stream) {
    const float* src = (const float*)d_in[0];   // [8,3,4096]
    const float* tgt = (const float*)d_in[1];   // [8,3,4096]
    float* out = (float*)d_out;                 // [8]

    zero_out_kernel<<<1, 64, 0, stream>>>(out);
    nn_loss_kernel<<<512, 256, 0, stream>>>(src, tgt, out);
}